// Round 2
// baseline (564.168 us; speedup 1.0000x reference)
//
#include <hip/hip_runtime.h>
#include <math.h>

#define NB 16
#define DD 256       // D (in channels)
#define LL 16384     // H*W
#define DO 256       // D_OUT
#define NCH 64       // l-chunks per image
#define CHL 256      // l per chunk
#define NT 4         // tiles per chunk
#define TL 64        // l per tile

// workspace float offsets
#define WS_QK    0                    // 256
#define WS_QW2   256                  // 256
#define WS_C1    512
#define WS_C2    513
#define WS_W1T   768                  // 65536  w1t[f][o]
#define WS_VWT   (WS_W1T + 65536)     // 65536  v_wt[d][o]
#define WS_PQ    (WS_VWT + 65536)     // 16384
#define WS_M     (WS_PQ + LL)         // NB*NCH = 1024
#define WS_DEN   (WS_M + NB*NCH)      // 1024
#define WS_NUM   (WS_DEN + NB*NCH)    // NB*NCH*256 = 262144
// total ~413k floats (~1.65 MB) of d_ws

__device__ __forceinline__ float gelu_tanh(float u) {
    float u3 = u*u*u;
    return 0.5f*u*(1.0f + tanhf(0.7978845608028654f*(u + 0.044715f*u3)));
}

// ---- K0a: grid 4. b0: qk[d]=sum_o k_w[o,d]q[o]; b1: qw2[j]=sum_o w2[o,j]q[o];
//           b2: c1=k_b.q; b3: c2=b2.q
__global__ __launch_bounds__(256) void k0a(const float* __restrict__ query,
        const float* __restrict__ k_w, const float* __restrict__ k_b,
        const float* __restrict__ w2, const float* __restrict__ b2,
        float* __restrict__ ws) {
    __shared__ float q_s[DO];
    __shared__ float red[256];
    int t = threadIdx.x, b = blockIdx.x;
    q_s[t] = query[t];
    __syncthreads();
    if (b == 0) {
        float a = 0.f;
        #pragma unroll 8
        for (int o = 0; o < DO; ++o) a += k_w[o*DD + t] * q_s[o];
        ws[WS_QK + t] = a;
    } else if (b == 1) {
        float a = 0.f;
        #pragma unroll 8
        for (int o = 0; o < DO; ++o) a += w2[o*DO + t] * q_s[o];
        ws[WS_QW2 + t] = a;
    } else if (b == 2) {
        red[t] = k_b[t]*q_s[t];
        __syncthreads();
        for (int s = 128; s > 0; s >>= 1) { if (t < s) red[t] += red[t+s]; __syncthreads(); }
        if (t == 0) ws[WS_C1] = red[0];
    } else {
        red[t] = b2[t]*q_s[t];
        __syncthreads();
        for (int s = 128; s > 0; s >>= 1) { if (t < s) red[t] += red[t+s]; __syncthreads(); }
        if (t == 0) ws[WS_C2] = red[0];
    }
}

// ---- K0b: transposes for coalesced later access. grid 512.
__global__ __launch_bounds__(256) void k0b(const float* __restrict__ w1,
        const float* __restrict__ v_w, float* __restrict__ ws) {
    int t = threadIdx.x, b = blockIdx.x;
    if (b < 256) {
        ws[WS_W1T + b*DO + t] = w1[t*DO + b];      // w1t[f][o] = w1[o][f]
    } else {
        int c = b - 256;
        ws[WS_VWT + c*DO + t] = v_w[t*DD + c];     // v_wt[d][o] = v_w[o][d]
    }
}

// ---- K1: pq[l] = gelu(feats[l] @ w1^T + b1) . qw2 + c2.  grid 512, 32 l per block.
__global__ __launch_bounds__(256) void k1_pq(const float* __restrict__ Wr,
        const float* __restrict__ b1, float* __restrict__ ws) {
    __shared__ float feats[32*256];   // 32 KB
    __shared__ float wbuf[32*256];    // 32 KB
    int t = threadIdx.x;
    int w = t >> 6, lane = t & 63;
    int l0 = blockIdx.x * 32;
    int r = t & 127;
    float wr0 = Wr[r*2], wr1 = Wr[r*2+1];
    bool is_cos = (t < 128);          // wave-uniform branch
    for (int lr = 0; lr < 32; ++lr) {
        int l = l0 + lr;
        int i = l >> 7, j = l & 127;
        float y = -1.0f + (2.0f/127.0f)*(float)i;
        float xg = -1.0f + (2.0f/127.0f)*(float)j;
        float p = y*wr0 + xg*wr1;
        feats[lr*256 + t] = (is_cos ? cosf(p) : sinf(p)) * 0.0625f;  // /sqrt(256)
    }
    int o4 = lane * 4;                // each wave covers all 256 o; wave owns 8 l's
    float z[8][4];
    #pragma unroll
    for (int a = 0; a < 8; ++a) { z[a][0]=0.f; z[a][1]=0.f; z[a][2]=0.f; z[a][3]=0.f; }
    __syncthreads();
    for (int fc = 0; fc < 8; ++fc) {
        // stage w1t[fc*32 .. +31][:] into LDS (each wave: one full 1KB row per i2)
        #pragma unroll
        for (int i2 = 0; i2 < 8; ++i2) {
            int idx = i2*256 + t;
            int fl = idx >> 6;
            int c = (idx & 63) * 4;
            *(float4*)(wbuf + fl*256 + c) =
                *(const float4*)(ws + WS_W1T + (fc*32+fl)*DO + c);
        }
        __syncthreads();
        for (int f = 0; f < 32; f += 2) {
            float4 wv0 = *(const float4*)(wbuf + f*256 + o4);       // ds_read_b128
            float4 wv1 = *(const float4*)(wbuf + (f+1)*256 + o4);
            #pragma unroll
            for (int lr = 0; lr < 8; ++lr) {
                float2 fv = *(const float2*)(feats + (w*8+lr)*256 + fc*32 + f); // b64 broadcast
                z[lr][0] += fv.x*wv0.x + fv.y*wv1.x;
                z[lr][1] += fv.x*wv0.y + fv.y*wv1.y;
                z[lr][2] += fv.x*wv0.z + fv.y*wv1.z;
                z[lr][3] += fv.x*wv0.w + fv.y*wv1.w;
            }
        }
        __syncthreads();
    }
    float4 b1v = *(const float4*)(b1 + o4);
    float4 qwv = *(const float4*)(ws + WS_QW2 + o4);
    float c2 = ws[WS_C2];
    #pragma unroll
    for (int lr = 0; lr < 8; ++lr) {
        float pp = gelu_tanh(z[lr][0]+b1v.x)*qwv.x + gelu_tanh(z[lr][1]+b1v.y)*qwv.y
                 + gelu_tanh(z[lr][2]+b1v.z)*qwv.z + gelu_tanh(z[lr][3]+b1v.w)*qwv.w;
        for (int off = 32; off > 0; off >>= 1) pp += __shfl_xor(pp, off);
        if (lane == 0) ws[WS_PQ + l0 + w*8 + lr] = pp + c2;
    }
}

// ---- K2: single pass over x, x-tile register-resident. grid 1024 = (n, chunk of 256 l),
// 4 tiles of 64 l per chunk. Online softmax partials per block.
__global__ __launch_bounds__(256,4) void k2_main(const float* __restrict__ x,
        float* __restrict__ ws) {
    __shared__ float part2[16*68];        // score partials [dld][l], stride 68 (align+bank-safe)
    __shared__ float e_s[64];
    __shared__ float numred[256*17];      // final d-reduction, +1 pad
    __shared__ float m_s, den_s, sc_s;
    int t = threadIdx.x;
    int n = blockIdx.x >> 6, ch = blockIdx.x & 63;
    const float* xb = x + (size_t)n * (size_t)(DD*LL);
    int dld = t >> 4;            // 0..15 : d = i2*16 + dld
    int li  = (t & 15) * 4;      // 0..60 : l-offset within tile
    float qkr[16];
    #pragma unroll
    for (int i2 = 0; i2 < 16; ++i2) qkr[i2] = ws[WS_QK + i2*16 + dld];
    float c1 = ws[WS_C1];
    if (t == 0) { m_s = -INFINITY; den_s = 0.f; sc_s = 0.f; }
    float num[16];
    #pragma unroll
    for (int i2 = 0; i2 < 16; ++i2) num[i2] = 0.f;

    for (int tb = 0; tb < NT; ++tb) {
        int l0 = ch*CHL + tb*TL;
        float4 xr[16];
        #pragma unroll
        for (int i2 = 0; i2 < 16; ++i2) {
            int d = i2*16 + dld;
            xr[i2] = *(const float4*)(xb + (size_t)d*LL + l0 + li);   // 4×256B rows/wave-instr
        }
        float4 sp = make_float4(0.f, 0.f, 0.f, 0.f);
        #pragma unroll
        for (int i2 = 0; i2 < 16; ++i2) {
            sp.x += xr[i2].x * qkr[i2];
            sp.y += xr[i2].y * qkr[i2];
            sp.z += xr[i2].z * qkr[i2];
            sp.w += xr[i2].w * qkr[i2];
        }
        *(float4*)(part2 + dld*68 + li) = sp;   // one b128/thread
        __syncthreads();
        if (t < 64) {                           // wave 0 finalizes this tile's scores
            float dot = 0.f;
            #pragma unroll
            for (int j = 0; j < 16; ++j) dot += part2[j*68 + t];   // 2 lanes/bank: free
            float score = (dot + c1 + ws[WS_PQ + l0 + t]) * 0.0625f;
            float mc = score;
            #pragma unroll
            for (int off = 32; off > 0; off >>= 1) mc = fmaxf(mc, __shfl_xor(mc, off));
            float mold = m_s;
            float mnew = fmaxf(mold, mc);
            float e = expf(score - mnew);
            e_s[t] = e;
            float dc = e;
            #pragma unroll
            for (int off = 32; off > 0; off >>= 1) dc += __shfl_xor(dc, off);
            if (t == 0) {
                float sc = expf(mold - mnew);   // first tile: exp(-inf)=0
                den_s = den_s*sc + dc;
                m_s = mnew;
                sc_s = sc;
            }
        }
        __syncthreads();
        float4 ef = *(const float4*)(e_s + li);
        float sc = sc_s;
        #pragma unroll
        for (int i2 = 0; i2 < 16; ++i2)
            num[i2] = num[i2]*sc
                    + xr[i2].x*ef.x + xr[i2].y*ef.y + xr[i2].z*ef.z + xr[i2].w*ef.w;
        __syncthreads();   // part2/e_s/sc_s safe for next tile
    }
    // reduce num over the 16 li-groups per d
    int g = t & 15;
    #pragma unroll
    for (int i2 = 0; i2 < 16; ++i2)
        numred[(i2*16 + dld)*17 + g] = num[i2];
    __syncthreads();
    float acc = 0.f;
    #pragma unroll
    for (int gg = 0; gg < 16; ++gg) acc += numred[t*17 + gg];
    int pb = n*NCH + ch;
    ws[WS_NUM + (size_t)pb*256 + t] = acc;     // coalesced
    if (t == 0) { ws[WS_M + pb] = m_s; ws[WS_DEN + pb] = den_s; }
}

// ---- K3: combine partials per n, then out[n,o] = v_w[o,:].s + v_b[o]. grid 16.
__global__ __launch_bounds__(256) void k3_final(const float* __restrict__ ws,
        const float* __restrict__ v_b, float* __restrict__ out) {
    __shared__ float s_s[DD];
    int t = threadIdx.x, n = blockIdx.x;
    float m = -INFINITY;
    for (int ch = 0; ch < NCH; ++ch) m = fmaxf(m, ws[WS_M + n*NCH + ch]);
    float den = 0.f;
    for (int ch = 0; ch < NCH; ++ch)
        den += ws[WS_DEN + n*NCH + ch] * expf(ws[WS_M + n*NCH + ch] - m);
    float sacc = 0.f;
    for (int ch = 0; ch < NCH; ++ch) {
        float sc = expf(ws[WS_M + n*NCH + ch] - m);
        sacc += ws[WS_NUM + (size_t)(n*NCH+ch)*256 + t] * sc;   // coalesced
    }
    s_s[t] = sacc / den;
    __syncthreads();
    float acc = v_b[t];
    #pragma unroll 8
    for (int d = 0; d < DD; ++d)
        acc += ws[WS_VWT + d*DO + t] * s_s[d];         // coalesced, s broadcast
    out[n*DO + t] = acc;
}

extern "C" void kernel_launch(void* const* d_in, const int* in_sizes, int n_in,
                              void* d_out, int out_size, void* d_ws, size_t ws_size,
                              hipStream_t stream) {
    const float* x     = (const float*)d_in[0];
    const float* query = (const float*)d_in[1];
    const float* k_w   = (const float*)d_in[2];
    const float* k_b   = (const float*)d_in[3];
    const float* v_w   = (const float*)d_in[4];
    const float* v_b   = (const float*)d_in[5];
    const float* Wr    = (const float*)d_in[6];
    const float* w1    = (const float*)d_in[7];
    const float* b1    = (const float*)d_in[8];
    const float* w2    = (const float*)d_in[9];
    const float* b2    = (const float*)d_in[10];
    float* ws  = (float*)d_ws;
    float* out = (float*)d_out;

    k0a<<<4, 256, 0, stream>>>(query, k_w, k_b, w2, b2, ws);
    k0b<<<512, 256, 0, stream>>>(w1, v_w, ws);
    k1_pq<<<512, 256, 0, stream>>>(Wr, b1, ws);
    k2_main<<<1024, 256, 0, stream>>>(x, ws);
    k3_final<<<16, 256, 0, stream>>>(ws, v_b, out);
}

// Round 4
// 489.755 us; speedup vs baseline: 1.1519x; 1.1519x over previous
//
#include <hip/hip_runtime.h>
#include <math.h>

#define NB 16
#define DD 256       // D (in channels)
#define LL 16384     // H*W
#define DO 256       // D_OUT
#define NCH 64       // l-chunks per image
#define CHL 256      // l per chunk
#define NT 4         // tiles per chunk
#define TL 64        // l per tile

// workspace float offsets
#define WS_QK    0                    // 256
#define WS_QW2   256                  // 256
#define WS_C1    512
#define WS_C2    513
#define WS_W1T   768                  // 65536  w1t[f][o]
#define WS_VWT   (WS_W1T + 65536)     // 65536  v_wt[d][o]
#define WS_PQ    (WS_VWT + 65536)     // 16384
#define WS_M     (WS_PQ + LL)         // NB*NCH = 1024
#define WS_DEN   (WS_M + NB*NCH)      // 1024
#define WS_NUM   (WS_DEN + NB*NCH)    // NB*NCH*256 = 262144
// total ~413k floats (~1.65 MB) of d_ws

__device__ __forceinline__ float gelu_tanh(float u) {
    float u3 = u*u*u;
    return 0.5f*u*(1.0f + tanhf(0.7978845608028654f*(u + 0.044715f*u3)));
}

// ---- K0a: grid 4. b0: qk[d]=sum_o k_w[o,d]q[o]; b1: qw2[j]=sum_o w2[o,j]q[o];
//           b2: c1=k_b.q; b3: c2=b2.q
__global__ __launch_bounds__(256) void k0a(const float* __restrict__ query,
        const float* __restrict__ k_w, const float* __restrict__ k_b,
        const float* __restrict__ w2, const float* __restrict__ b2,
        float* __restrict__ ws) {
    __shared__ float q_s[DO];
    __shared__ float red[256];
    int t = threadIdx.x, b = blockIdx.x;
    q_s[t] = query[t];
    __syncthreads();
    if (b == 0) {
        float a = 0.f;
        #pragma unroll 8
        for (int o = 0; o < DO; ++o) a += k_w[o*DD + t] * q_s[o];
        ws[WS_QK + t] = a;
    } else if (b == 1) {
        float a = 0.f;
        #pragma unroll 8
        for (int o = 0; o < DO; ++o) a += w2[o*DO + t] * q_s[o];
        ws[WS_QW2 + t] = a;
    } else if (b == 2) {
        red[t] = k_b[t]*q_s[t];
        __syncthreads();
        for (int s = 128; s > 0; s >>= 1) { if (t < s) red[t] += red[t+s]; __syncthreads(); }
        if (t == 0) ws[WS_C1] = red[0];
    } else {
        red[t] = b2[t]*q_s[t];
        __syncthreads();
        for (int s = 128; s > 0; s >>= 1) { if (t < s) red[t] += red[t+s]; __syncthreads(); }
        if (t == 0) ws[WS_C2] = red[0];
    }
}

// ---- K0b: transposes for coalesced later access. grid 512.
__global__ __launch_bounds__(256) void k0b(const float* __restrict__ w1,
        const float* __restrict__ v_w, float* __restrict__ ws) {
    int t = threadIdx.x, b = blockIdx.x;
    if (b < 256) {
        ws[WS_W1T + b*DO + t] = w1[t*DO + b];      // w1t[f][o] = w1[o][f]
    } else {
        int c = b - 256;
        ws[WS_VWT + c*DO + t] = v_w[t*DD + c];     // v_wt[d][o] = v_w[o][d]
    }
}

// ---- K1: pq[l] = gelu(feats[l] @ w1^T + b1) . qw2 + c2.  grid 512, 32 l per block.
__global__ __launch_bounds__(256) void k1_pq(const float* __restrict__ Wr,
        const float* __restrict__ b1, float* __restrict__ ws) {
    __shared__ float feats[32*256];   // 32 KB
    __shared__ float wbuf[32*256];    // 32 KB
    int t = threadIdx.x;
    int w = t >> 6, lane = t & 63;
    int l0 = blockIdx.x * 32;
    int r = t & 127;
    float wr0 = Wr[r*2], wr1 = Wr[r*2+1];
    bool is_cos = (t < 128);          // wave-uniform branch
    for (int lr = 0; lr < 32; ++lr) {
        int l = l0 + lr;
        int i = l >> 7, j = l & 127;
        float y = -1.0f + (2.0f/127.0f)*(float)i;
        float xg = -1.0f + (2.0f/127.0f)*(float)j;
        float p = y*wr0 + xg*wr1;
        feats[lr*256 + t] = (is_cos ? cosf(p) : sinf(p)) * 0.0625f;  // /sqrt(256)
    }
    int o4 = lane * 4;                // each wave covers all 256 o; wave owns 8 l's
    float z[8][4];
    #pragma unroll
    for (int a = 0; a < 8; ++a) { z[a][0]=0.f; z[a][1]=0.f; z[a][2]=0.f; z[a][3]=0.f; }
    __syncthreads();
    for (int fc = 0; fc < 8; ++fc) {
        // stage w1t[fc*32 .. +31][:] into LDS (each wave: one full 1KB row per i2)
        #pragma unroll
        for (int i2 = 0; i2 < 8; ++i2) {
            int idx = i2*256 + t;
            int fl = idx >> 6;
            int c = (idx & 63) * 4;
            *(float4*)(wbuf + fl*256 + c) =
                *(const float4*)(ws + WS_W1T + (fc*32+fl)*DO + c);
        }
        __syncthreads();
        for (int f = 0; f < 32; f += 2) {
            float4 wv0 = *(const float4*)(wbuf + f*256 + o4);       // ds_read_b128
            float4 wv1 = *(const float4*)(wbuf + (f+1)*256 + o4);
            #pragma unroll
            for (int lr = 0; lr < 8; ++lr) {
                float2 fv = *(const float2*)(feats + (w*8+lr)*256 + fc*32 + f); // b64 broadcast
                z[lr][0] += fv.x*wv0.x + fv.y*wv1.x;
                z[lr][1] += fv.x*wv0.y + fv.y*wv1.y;
                z[lr][2] += fv.x*wv0.z + fv.y*wv1.z;
                z[lr][3] += fv.x*wv0.w + fv.y*wv1.w;
            }
        }
        __syncthreads();
    }
    float4 b1v = *(const float4*)(b1 + o4);
    float4 qwv = *(const float4*)(ws + WS_QW2 + o4);
    float c2 = ws[WS_C2];
    #pragma unroll
    for (int lr = 0; lr < 8; ++lr) {
        float pp = gelu_tanh(z[lr][0]+b1v.x)*qwv.x + gelu_tanh(z[lr][1]+b1v.y)*qwv.y
                 + gelu_tanh(z[lr][2]+b1v.z)*qwv.z + gelu_tanh(z[lr][3]+b1v.w)*qwv.w;
        for (int off = 32; off > 0; off >>= 1) pp += __shfl_xor(pp, off);
        if (lane == 0) ws[WS_PQ + l0 + w*8 + lr] = pp + c2;
    }
}

// ---- K2: single pass over x, x-tile register-resident. grid 1024 = (n, chunk of 256 l),
// 4 tiles of 64 l. Per-wave redundant online softmax (m/den/sc wave-uniform regs).
// __launch_bounds__(256,3): VGPR cap ~168 — the (256,4)=128 cap spilled xr[16] to
// scratch (R2: WRITE_SIZE 195MB). 3 blocks/CU is plenty for a streaming kernel.
__global__ __launch_bounds__(256,3) void k2_main(const float* __restrict__ x,
        float* __restrict__ ws) {
    __shared__ float part2[16*68];        // score partials [dld][l], stride 68
    __shared__ float e_s[64];
    __shared__ float numred[256*17];      // final d-reduction, +1 pad
    int t = threadIdx.x;
    int lane = t & 63;
    int n = blockIdx.x >> 6, ch = blockIdx.x & 63;
    const float* xb = x + (size_t)n * (size_t)(DD*LL);
    int dld = t >> 4;            // 0..15 : d = i2*16 + dld
    int li  = (t & 15) * 4;      // 0..60 : l-offset within tile
    float qkr[16];
    #pragma unroll
    for (int i2 = 0; i2 < 16; ++i2) qkr[i2] = ws[WS_QK + i2*16 + dld];
    float c1 = ws[WS_C1];
    float m_w = -INFINITY, den_w = 0.f;   // wave-uniform (redundant per wave)
    float num[16];
    #pragma unroll
    for (int i2 = 0; i2 < 16; ++i2) num[i2] = 0.f;

    for (int tb = 0; tb < NT; ++tb) {
        int l0 = ch*CHL + tb*TL;
        float4 xr[16];
        #pragma unroll
        for (int i2 = 0; i2 < 16; ++i2) {
            int d = i2*16 + dld;
            xr[i2] = *(const float4*)(xb + (size_t)d*LL + l0 + li);   // 4×256B rows/wave-instr
        }
        float4 sp = make_float4(0.f, 0.f, 0.f, 0.f);
        #pragma unroll
        for (int i2 = 0; i2 < 16; ++i2) {
            sp.x += xr[i2].x * qkr[i2];
            sp.y += xr[i2].y * qkr[i2];
            sp.z += xr[i2].z * qkr[i2];
            sp.w += xr[i2].w * qkr[i2];
        }
        *(float4*)(part2 + dld*68 + li) = sp;   // one b128/thread
        __syncthreads();
        // every wave computes scores for l = lane (redundant across waves, no cross-wave sync)
        {
            float dot = 0.f;
            #pragma unroll
            for (int j = 0; j < 16; ++j) dot += part2[j*68 + lane];   // 2 lanes/bank: free
            float score = (dot + c1 + ws[WS_PQ + l0 + lane]) * 0.0625f;
            float mc = score;
            #pragma unroll
            for (int off = 32; off > 0; off >>= 1) mc = fmaxf(mc, __shfl_xor(mc, off));
            float mnew = fmaxf(m_w, mc);
            float e = expf(score - mnew);
            e_s[lane] = e;                       // 4 waves write identical values: benign
            float dc = e;
            #pragma unroll
            for (int off = 32; off > 0; off >>= 1) dc += __shfl_xor(dc, off);
            float sc = expf(m_w - mnew);         // first tile: exp(-inf)=0
            den_w = den_w*sc + dc;
            m_w = mnew;
            #pragma unroll
            for (int i2 = 0; i2 < 16; ++i2) num[i2] *= sc;
        }
        __syncthreads();    // e_s ready; also fences part2 reads before next tile's writes
        float4 ef = *(const float4*)(e_s + li);
        #pragma unroll
        for (int i2 = 0; i2 < 16; ++i2)
            num[i2] += xr[i2].x*ef.x + xr[i2].y*ef.y + xr[i2].z*ef.z + xr[i2].w*ef.w;
    }
    // reduce num over the 16 li-groups per d
    __syncthreads();
    int g = t & 15;
    #pragma unroll
    for (int i2 = 0; i2 < 16; ++i2)
        numred[(i2*16 + dld)*17 + g] = num[i2];
    __syncthreads();
    float acc = 0.f;
    #pragma unroll
    for (int gg = 0; gg < 16; ++gg) acc += numred[t*17 + gg];
    int pb = n*NCH + ch;
    ws[WS_NUM + (size_t)pb*256 + t] = acc;     // coalesced
    if (t == 0) { ws[WS_M + pb] = m_w; ws[WS_DEN + pb] = den_w; }
}

// ---- K3: combine partials per n, then out[n,o] = v_w[o,:].s + v_b[o]. grid 16.
__global__ __launch_bounds__(256) void k3_final(const float* __restrict__ ws,
        const float* __restrict__ v_b, float* __restrict__ out) {
    __shared__ float s_s[DD];
    int t = threadIdx.x, n = blockIdx.x;
    float m = -INFINITY;
    for (int ch = 0; ch < NCH; ++ch) m = fmaxf(m, ws[WS_M + n*NCH + ch]);
    float den = 0.f;
    for (int ch = 0; ch < NCH; ++ch)
        den += ws[WS_DEN + n*NCH + ch] * expf(ws[WS_M + n*NCH + ch] - m);
    float sacc = 0.f;
    for (int ch = 0; ch < NCH; ++ch) {
        float sc = expf(ws[WS_M + n*NCH + ch] - m);
        sacc += ws[WS_NUM + (size_t)(n*NCH+ch)*256 + t] * sc;   // coalesced
    }
    s_s[t] = sacc / den;
    __syncthreads();
    float acc = v_b[t];
    #pragma unroll 8
    for (int d = 0; d < DD; ++d)
        acc += ws[WS_VWT + d*DO + t] * s_s[d];         // coalesced, s broadcast
    out[n*DO + t] = acc;
}

extern "C" void kernel_launch(void* const* d_in, const int* in_sizes, int n_in,
                              void* d_out, int out_size, void* d_ws, size_t ws_size,
                              hipStream_t stream) {
    const float* x     = (const float*)d_in[0];
    const float* query = (const float*)d_in[1];
    const float* k_w   = (const float*)d_in[2];
    const float* k_b   = (const float*)d_in[3];
    const float* v_w   = (const float*)d_in[4];
    const float* v_b   = (const float*)d_in[5];
    const float* Wr    = (const float*)d_in[6];
    const float* w1    = (const float*)d_in[7];
    const float* b1    = (const float*)d_in[8];
    const float* w2    = (const float*)d_in[9];
    const float* b2    = (const float*)d_in[10];
    float* ws  = (float*)d_ws;
    float* out = (float*)d_out;

    k0a<<<4, 256, 0, stream>>>(query, k_w, k_b, w2, b2, ws);
    k0b<<<512, 256, 0, stream>>>(w1, v_w, ws);
    k1_pq<<<512, 256, 0, stream>>>(Wr, b1, ws);
    k2_main<<<1024, 256, 0, stream>>>(x, ws);
    k3_final<<<16, 256, 0, stream>>>(ws, v_b, out);
}